// Round 1
// baseline (167.825 us; speedup 1.0000x reference)
//
#include <hip/hip_runtime.h>

#define NHEAD 32      // B*H
#define SEQ   2048
#define DHEAD 64
#define QBLK  64      // q rows per block (4 waves x 16)
#define KVBLK 64      // kv rows per tile
#define NWAVE 4

typedef _Float16 half8 __attribute__((ext_vector_type(8)));
typedef float    f32x4 __attribute__((ext_vector_type(4)));

__device__ __forceinline__ half8 pack8(float4 a, float4 b) {
    half8 f;
    f[0] = (_Float16)a.x; f[1] = (_Float16)a.y; f[2] = (_Float16)a.z; f[3] = (_Float16)a.w;
    f[4] = (_Float16)b.x; f[5] = (_Float16)b.y; f[6] = (_Float16)b.z; f[7] = (_Float16)b.w;
    return f;
}

__global__ __launch_bounds__(256, 2)
void fattn_fwd(const float* __restrict__ Qg, const float* __restrict__ Kg,
               const float* __restrict__ Vg, float* __restrict__ Og)
{
    __shared__ __align__(16) _Float16 klds[KVBLK * DHEAD];
    __shared__ __align__(16) _Float16 vlds[KVBLK * DHEAD];
    __shared__ __align__(16) _Float16 plds[NWAVE * 16 * KVBLK];

    const int tid  = threadIdx.x;
    const int wave = tid >> 6;
    const int lane = tid & 63;
    const int g    = lane >> 4;   // 4 lane-groups
    const int ln   = lane & 15;

    const int head = blockIdx.x >> 5;   // 32 q-blocks per head (same-head blocks adjacent for L2)
    const int qb   = blockIdx.x & 31;
    const size_t hbase = (size_t)head * SEQ * DHEAD;

    const int q0 = qb * QBLK + wave * 16;   // this wave's first q row (within head)

    // ---- Q fragments, pre-scaled by 1/sqrt(D)=0.125 ----
    half8 qfrag[2];
    {
        const float* qrow = Qg + hbase + (size_t)(q0 + ln) * DHEAD + g * 8;
        #pragma unroll
        for (int ks = 0; ks < 2; ++ks) {
            float4 a = *(const float4*)(qrow + 32 * ks);
            float4 b = *(const float4*)(qrow + 32 * ks + 4);
            a.x *= 0.125f; a.y *= 0.125f; a.z *= 0.125f; a.w *= 0.125f;
            b.x *= 0.125f; b.y *= 0.125f; b.z *= 0.125f; b.w *= 0.125f;
            qfrag[ks] = pack8(a, b);
        }
    }

    f32x4 accO[4] = {};                     // 16 q rows x 64 d, C/D layout
    float m_run[4] = {-1e30f, -1e30f, -1e30f, -1e30f};
    float l_run[4] = {0.f, 0.f, 0.f, 0.f};

    // staging assignment: thread -> (row, 16-float column group)
    const int srow = tid >> 2;
    const int scg  = tid & 3;
    const int swz  = (srow & 7) << 3;       // XOR swizzle in shorts (16B granules)
    const float* kb_g = Kg + hbase + (size_t)srow * DHEAD + scg * 16;
    const float* vb_g = Vg + hbase + (size_t)srow * DHEAD + scg * 16;
    _Float16* kw0 = &klds[srow * DHEAD + ((scg * 16)     ^ swz)];
    _Float16* kw1 = &klds[srow * DHEAD + ((scg * 16 + 8) ^ swz)];
    _Float16* vw0 = &vlds[srow * DHEAD + ((scg * 16)     ^ swz)];
    _Float16* vw1 = &vlds[srow * DHEAD + ((scg * 16 + 8) ^ swz)];
    _Float16* pw  = &plds[wave * 16 * KVBLK];

    for (int t = 0; t < SEQ / KVBLK; ++t) {
        __syncthreads();   // protect klds/vlds from previous iteration's readers
        {
            const float4* k4 = (const float4*)(kb_g + (size_t)t * KVBLK * DHEAD);
            const float4* v4 = (const float4*)(vb_g + (size_t)t * KVBLK * DHEAD);
            float4 ka = k4[0], kbv = k4[1], kc = k4[2], kd = k4[3];
            float4 va = v4[0], vbv = v4[1], vc = v4[2], vd = v4[3];
            *(half8*)kw0 = pack8(ka, kbv);
            *(half8*)kw1 = pack8(kc, kd);
            *(half8*)vw0 = pack8(va, vbv);
            *(half8*)vw1 = pack8(vc, vd);
        }
        __syncthreads();

        // ---- S = (Q/8) K^T : 4 n-tiles x 2 k-steps ----
        f32x4 sacc[4] = {};
        #pragma unroll
        for (int n = 0; n < 4; ++n) {
            const int kv = ln + 16 * n;
            const _Float16* krow = &klds[kv * DHEAD];
            const int ksw = (kv & 7) << 3;
            #pragma unroll
            for (int ks = 0; ks < 2; ++ks) {
                half8 kf = *(const half8*)&krow[(8 * g + 32 * ks) ^ ksw];
                sacc[n] = __builtin_amdgcn_mfma_f32_16x16x32_f16(qfrag[ks], kf, sacc[n], 0, 0, 0);
            }
        }

        // ---- online softmax (rows live on 16-lane subgroups) ----
        float alpha[4];
        #pragma unroll
        for (int r = 0; r < 4; ++r) {
            float v = fmaxf(fmaxf(sacc[0][r], sacc[1][r]), fmaxf(sacc[2][r], sacc[3][r]));
            v = fmaxf(v, __shfl_xor(v, 1, 64));
            v = fmaxf(v, __shfl_xor(v, 2, 64));
            v = fmaxf(v, __shfl_xor(v, 4, 64));
            v = fmaxf(v, __shfl_xor(v, 8, 64));
            const float mn = fmaxf(m_run[r], v);
            alpha[r] = __expf(m_run[r] - mn);
            m_run[r] = mn;
        }
        #pragma unroll
        for (int n = 0; n < 4; ++n) {
            #pragma unroll
            for (int r = 0; r < 4; ++r)
                sacc[n][r] = __expf(sacc[n][r] - m_run[r]);
        }
        #pragma unroll
        for (int r = 0; r < 4; ++r) {
            float s = (sacc[0][r] + sacc[1][r]) + (sacc[2][r] + sacc[3][r]);
            s += __shfl_xor(s, 1, 64);
            s += __shfl_xor(s, 2, 64);
            s += __shfl_xor(s, 4, 64);
            s += __shfl_xor(s, 8, 64);
            l_run[r] = l_run[r] * alpha[r] + s;
        }
        #pragma unroll
        for (int dn = 0; dn < 4; ++dn) {
            f32x4 o = accO[dn];
            o[0] *= alpha[0]; o[1] *= alpha[1]; o[2] *= alpha[2]; o[3] *= alpha[3];
            accO[dn] = o;
        }

        // ---- P -> per-wave LDS (f16, swizzled), re-layout C/D -> A-frag ----
        #pragma unroll
        for (int n = 0; n < 4; ++n) {
            const int kv = ln + 16 * n;
            #pragma unroll
            for (int r = 0; r < 4; ++r) {
                const int q = 4 * g + r;
                pw[q * KVBLK + (kv ^ ((q & 7) << 3))] = (_Float16)sacc[n][r];
            }
        }
        // same-wave LDS RAW: in-order DS pipe + compiler waitcnt, no barrier needed

        // ---- O += P V ----
        #pragma unroll
        for (int ks = 0; ks < 2; ++ks) {
            half8 pf = *(const half8*)&pw[ln * KVBLK + ((8 * g + 32 * ks) ^ ((ln & 7) << 3))];
            #pragma unroll
            for (int dn = 0; dn < 4; ++dn) {
                const int d = ln + 16 * dn;
                half8 vf;
                #pragma unroll
                for (int j = 0; j < 8; ++j) {
                    const int kv = 8 * g + 32 * ks + j;   // kv&7 == j
                    vf[j] = vlds[kv * DHEAD + (d ^ (j << 3))];
                }
                accO[dn] = __builtin_amdgcn_mfma_f32_16x16x32_f16(pf, vf, accO[dn], 0, 0, 0);
            }
        }
    }

    // ---- epilogue: O / l ----
    float invl[4];
    #pragma unroll
    for (int r = 0; r < 4; ++r) invl[r] = 1.f / l_run[r];
    #pragma unroll
    for (int dn = 0; dn < 4; ++dn) {
        #pragma unroll
        for (int r = 0; r < 4; ++r) {
            Og[hbase + (size_t)(q0 + 4 * g + r) * DHEAD + ln + 16 * dn] = accO[dn][r] * invl[r];
        }
    }
}

extern "C" void kernel_launch(void* const* d_in, const int* in_sizes, int n_in,
                              void* d_out, int out_size, void* d_ws, size_t ws_size,
                              hipStream_t stream) {
    const float* Q = (const float*)d_in[0];
    const float* K = (const float*)d_in[1];
    const float* V = (const float*)d_in[2];
    float* O = (float*)d_out;
    dim3 grid(NHEAD * (SEQ / QBLK));   // 32 heads * 32 q-blocks = 1024
    fattn_fwd<<<grid, 256, 0, stream>>>(Q, K, V, O);
}

// Round 3
// 71.099 us; speedup vs baseline: 2.3604x; 2.3604x over previous
//
#include <hip/hip_runtime.h>

#define SEQ   2048
#define DHEAD 64
#define QBLK  128
#define KVBLK 64
#define NT    (SEQ / KVBLK)

typedef _Float16 half4v __attribute__((ext_vector_type(4)));
typedef _Float16 half8  __attribute__((ext_vector_type(8)));
typedef float    f32x16 __attribute__((ext_vector_type(16)));
typedef unsigned u32;

__device__ __forceinline__ u32 cvt2(float x, float y) {
    return __builtin_bit_cast(u32, __builtin_amdgcn_cvt_pkrtz(x, y));
}

__device__ __forceinline__ half8 pack8(float4 a, float4 b) {
    union { u32 w[4]; half8 h; } r;
    r.w[0] = cvt2(a.x, a.y);
    r.w[1] = cvt2(a.z, a.w);
    r.w[2] = cvt2(b.x, b.y);
    r.w[3] = cvt2(b.z, b.w);
    return r.h;
}

__global__ __launch_bounds__(256, 2)
void fattn_fwd(const float* __restrict__ Qg, const float* __restrict__ Kg,
               const float* __restrict__ Vg, float* __restrict__ Og)
{
    __shared__ __align__(16) _Float16 klds[KVBLK * DHEAD];  // row-major, granule-XOR-swizzled
    __shared__ __align__(16) _Float16 vlds[KVBLK * DHEAD];  // tr-subtiled [psub][4][16]

    const int tid  = threadIdx.x;
    const int wave = tid >> 6;
    const int lane = tid & 63;
    const int lq   = lane & 31;   // q (and d) fragment index
    const int h    = lane >> 5;   // k-half of the wave

    // XCD-bijective swizzle: 512 blocks, 64 per XCD = 4 whole heads per XCD
    const int bid = blockIdx.x;
    const int swz = (bid & 7) * 64 + (bid >> 3);
    const int head = swz >> 4;                  // 16 q-blocks per head
    const int qb   = swz & 15;
    const size_t hbase = (size_t)head * (SEQ * DHEAD);
    const int q0 = qb * QBLK + wave * 32;

    // ---- Q B-fragments, pre-scaled by 1/sqrt(D) ----
    half8 qf[4];
    {
        const float* qrow = Qg + hbase + (size_t)(q0 + lq) * DHEAD;
        const float sc = 0.125f;
        #pragma unroll
        for (int ks = 0; ks < 4; ++ks) {
            float4 a = *(const float4*)(qrow + 16*ks + 8*h);
            float4 b = *(const float4*)(qrow + 16*ks + 8*h + 4);
            a.x*=sc; a.y*=sc; a.z*=sc; a.w*=sc;
            b.x*=sc; b.y*=sc; b.z*=sc; b.w*=sc;
            qf[ks] = pack8(a, b);
        }
    }

    f32x16 accO[2];
    #pragma unroll
    for (int dm = 0; dm < 2; ++dm)
        #pragma unroll
        for (int i = 0; i < 16; ++i) accO[dm][i] = 0.f;
    float m_run = -1e30f, l_run = 0.f;

    // ---- staging mapping: thread -> (kv row, 16-float d-group) ----
    const int srow = tid >> 2;
    const int scg  = tid & 3;
    const float* kg0 = Kg + hbase + (size_t)srow * DHEAD + scg * 16;
    const float* vg0 = Vg + hbase + (size_t)srow * DHEAD + scg * 16;
    _Float16* kw0 = &klds[srow*64 + (((2*scg)   ^ (srow & 7)) << 3)];
    _Float16* kw1 = &klds[srow*64 + (((2*scg+1) ^ (srow & 7)) << 3)];
    const int kv4  = srow >> 2;
    const int psub = 16*(kv4>>2) + 8*(kv4&1) + 4*(scg>>1) + 2*((kv4>>1)&1) + (scg&1);
    _Float16* vw0 = &vlds[psub*64 + (srow & 3)*16];
    _Float16* vw1 = vw0 + 8;

    const int ksw = (lq & 7) << 3;
    const u32 vbase = (u32)(size_t)(&vlds[0]) + (u32)lane * 8u;

    // prologue: load tile 0 into regs
    float4 kr0,kr1,kr2,kr3, vr0,vr1,vr2,vr3;
    kr0 = *(const float4*)(kg0+0); kr1 = *(const float4*)(kg0+4);
    kr2 = *(const float4*)(kg0+8); kr3 = *(const float4*)(kg0+12);
    vr0 = *(const float4*)(vg0+0); vr1 = *(const float4*)(vg0+4);
    vr2 = *(const float4*)(vg0+8); vr3 = *(const float4*)(vg0+12);

    #pragma unroll 1
    for (int t = 0; t < NT; ++t) {
        __syncthreads();   // readers of previous tile done
        *(half8*)kw0 = pack8(kr0, kr1);
        *(half8*)kw1 = pack8(kr2, kr3);
        *(half8*)vw0 = pack8(vr0, vr1);
        *(half8*)vw1 = pack8(vr2, vr3);
        if (t + 1 < NT) {   // prefetch of next tile under this tile's compute
            const float* kp = kg0 + (size_t)(t+1) * (KVBLK * DHEAD);
            const float* vp = vg0 + (size_t)(t+1) * (KVBLK * DHEAD);
            kr0 = *(const float4*)(kp+0); kr1 = *(const float4*)(kp+4);
            kr2 = *(const float4*)(kp+8); kr3 = *(const float4*)(kp+12);
            vr0 = *(const float4*)(vp+0); vr1 = *(const float4*)(vp+4);
            vr2 = *(const float4*)(vp+8); vr3 = *(const float4*)(vp+12);
        }
        __syncthreads();   // tile t staged

        // ---- S^T = K · Q^T : 2 kv m-tiles x 4 k-steps ----
        f32x16 sacc[2];
        #pragma unroll
        for (int n = 0; n < 2; ++n) {
            #pragma unroll
            for (int i = 0; i < 16; ++i) sacc[n][i] = 0.f;
            #pragma unroll
            for (int ks = 0; ks < 4; ++ks) {
                half8 kf = *(const half8*)&klds[(32*n + lq)*64 + ((16*ks + 8*h) ^ ksw)];
                sacc[n] = __builtin_amdgcn_mfma_f32_32x32x16_f16(kf, qf[ks], sacc[n], 0, 0, 0);
            }
        }

        // ---- online softmax: q = lq is lane-local; kv split across h ----
        float mx = sacc[0][0];
        #pragma unroll
        for (int i = 1; i < 16; ++i) mx = fmaxf(mx, sacc[0][i]);
        #pragma unroll
        for (int i = 0; i < 16; ++i) mx = fmaxf(mx, sacc[1][i]);
        mx = fmaxf(mx, __shfl_xor(mx, 32, 64));
        const float mnew = fmaxf(m_run, mx);
        const float alpha = __expf(m_run - mnew);
        m_run = mnew;
        #pragma unroll
        for (int n = 0; n < 2; ++n)
            #pragma unroll
            for (int i = 0; i < 16; ++i) sacc[n][i] = __expf(sacc[n][i] - mnew);
        #pragma unroll
        for (int dm = 0; dm < 2; ++dm)
            #pragma unroll
            for (int i = 0; i < 16; ++i) accO[dm][i] *= alpha;
        {
            float lsum = 0.f;
            #pragma unroll
            for (int n = 0; n < 2; ++n)
                #pragma unroll
                for (int i = 0; i < 16; ++i) lsum += sacc[n][i];
            l_run = l_run * alpha + lsum;
        }

        // pack P to f16 word pairs: c[n][b][rp] = regs (4b+2rp, 4b+2rp+1)
        u32 c[2][4][2];
        #pragma unroll
        for (int n = 0; n < 2; ++n)
            #pragma unroll
            for (int b = 0; b < 4; ++b)
                #pragma unroll
                for (int rp = 0; rp < 2; ++rp)
                    c[n][b][rp] = cvt2(sacc[n][4*b+2*rp], sacc[n][4*b+2*rp+1]);

        // ---- P^T B-fragments via lane<->lane+32 exchange (no LDS) ----
        half8 pb[4];
        #pragma unroll
        for (int ks2 = 0; ks2 < 4; ++ks2) {
            const int n = ks2 >> 1, k1 = ks2 & 1;
            union { u32 w[4]; half8 h; } pu;
            #pragma unroll
            for (int rp = 0; rp < 2; ++rp) {
                const u32 lo = c[n][2*k1][rp], hi = c[n][2*k1+1][rp];
                const u32 keep = h ? hi : lo;
                const u32 send = h ? lo : hi;
                const u32 other = (u32)__shfl_xor((int)send, 32, 64);
                pu.w[rp]   = h ? other : keep;   // slots for k-half 0
                pu.w[2+rp] = h ? keep  : other;  // slots for k-half 1
            }
            pb[ks2] = pu.h;
        }

        // ---- O^T += V^T · P^T : V via hardware transpose reads ----
        half4v t000,t001,t010,t011,t100,t101,t110,t111,
               t200,t201,t210,t211,t300,t301,t310,t311;
        #define TRR(dst, IMM) \
            asm volatile("ds_read_b64_tr_b16 %0, %1 offset:" #IMM : "=v"(dst) : "v"(vbase) : "memory")
        TRR(t000,    0); TRR(t001, 1024); TRR(t010,  512); TRR(t011, 1536);
        TRR(t100, 2048); TRR(t101, 3072); TRR(t110, 2560); TRR(t111, 3584);
        TRR(t200, 4096); TRR(t201, 5120); TRR(t210, 4608); TRR(t211, 5632);
        TRR(t300, 6144); TRR(t301, 7168); TRR(t310, 6656); TRR(t311, 7680);
        #undef TRR
        asm volatile("s_waitcnt lgkmcnt(0)" ::: "memory");
        __builtin_amdgcn_sched_barrier(0);

        #define PVM(ks, dm, ta, tb) { half8 vv;                                   \
            vv[0]=ta[0]; vv[1]=ta[1]; vv[2]=ta[2]; vv[3]=ta[3];                    \
            vv[4]=tb[0]; vv[5]=tb[1]; vv[6]=tb[2]; vv[7]=tb[3];                    \
            accO[dm] = __builtin_amdgcn_mfma_f32_32x32x16_f16(vv, pb[ks], accO[dm], 0, 0, 0); }
        PVM(0,0,t000,t001) PVM(0,1,t010,t011)
        PVM(1,0,t100,t101) PVM(1,1,t110,t111)
        PVM(2,0,t200,t201) PVM(2,1,t210,t211)
        PVM(3,0,t300,t301) PVM(3,1,t310,t311)
        #undef PVM
    }

    // ---- epilogue ----
    const float ltot = l_run + __shfl_xor(l_run, 32, 64);
    const float inv = 1.0f / ltot;
    float* orow = Og + hbase + (size_t)(q0 + lq) * DHEAD;
    #pragma unroll
    for (int dm = 0; dm < 2; ++dm)
        #pragma unroll
        for (int b = 0; b < 4; ++b) {
            float4 o;
            o.x = accO[dm][4*b+0] * inv;
            o.y = accO[dm][4*b+1] * inv;
            o.z = accO[dm][4*b+2] * inv;
            o.w = accO[dm][4*b+3] * inv;
            *(float4*)(orow + 32*dm + 8*b + 4*h) = o;
        }
}

extern "C" void kernel_launch(void* const* d_in, const int* in_sizes, int n_in,
                              void* d_out, int out_size, void* d_ws, size_t ws_size,
                              hipStream_t stream) {
    const float* Q = (const float*)d_in[0];
    const float* K = (const float*)d_in[1];
    const float* V = (const float*)d_in[2];
    float* O = (float*)d_out;
    dim3 grid(32 * (SEQ / QBLK));   // 32 heads * 16 q-blocks = 512
    fattn_fwd<<<grid, 256, 0, stream>>>(Q, K, V, O);
}

// Round 4
// 67.153 us; speedup vs baseline: 2.4991x; 1.0588x over previous
//
#include <hip/hip_runtime.h>

#define SEQ   2048
#define DHEAD 64
#define QBLK  128
#define KVBLK 64
#define NT    (SEQ / KVBLK)
#define TILE_H (KVBLK * DHEAD)   // halves per K or V tile (4096 = 8KB)

typedef _Float16 half4v __attribute__((ext_vector_type(4)));
typedef _Float16 half8  __attribute__((ext_vector_type(8)));
typedef float    f32x16 __attribute__((ext_vector_type(16)));
typedef unsigned u32;

__device__ __forceinline__ u32 cvt2(float x, float y) {
    return __builtin_bit_cast(u32, __builtin_amdgcn_cvt_pkrtz(x, y));
}

__device__ __forceinline__ half8 pack8(float4 a, float4 b) {
    union { u32 w[4]; half8 h; } r;
    r.w[0] = cvt2(a.x, a.y);
    r.w[1] = cvt2(a.z, a.w);
    r.w[2] = cvt2(b.x, b.y);
    r.w[3] = cvt2(b.z, b.w);
    return r.h;
}

__device__ __forceinline__ float fexp2(float x) {
#if __has_builtin(__builtin_amdgcn_exp2f)
    return __builtin_amdgcn_exp2f(x);
#else
    return exp2f(x);
#endif
}

__global__ __launch_bounds__(256, 2)
void fattn_fwd(const float* __restrict__ Qg, const float* __restrict__ Kg,
               const float* __restrict__ Vg, float* __restrict__ Og)
{
    __shared__ __align__(16) _Float16 klds[2][TILE_H];  // row-major, granule-XOR-swizzled
    __shared__ __align__(16) _Float16 vlds[2][TILE_H];  // tr-subtiled [psub][4][16]

    const int tid  = threadIdx.x;
    const int wave = tid >> 6;
    const int lane = tid & 63;
    const int lq   = lane & 31;   // q (and d) fragment index
    const int h    = lane >> 5;   // k-half of the wave

    // XCD-bijective swizzle: 512 blocks, 64 per XCD = 4 whole heads per XCD
    const int bid = blockIdx.x;
    const int swz = (bid & 7) * 64 + (bid >> 3);
    const int head = swz >> 4;                  // 16 q-blocks per head
    const int qb   = swz & 15;
    const size_t hbase = (size_t)head * (SEQ * DHEAD);
    const int q0 = qb * QBLK + wave * 32;

    // ---- Q B-fragments, pre-scaled by log2e/sqrt(D) (exp2-domain softmax) ----
    half8 qf[4];
    {
        const float* qrow = Qg + hbase + (size_t)(q0 + lq) * DHEAD;
        const float sc = 0.125f * 1.44269504088896f;
        #pragma unroll
        for (int ks = 0; ks < 4; ++ks) {
            float4 a = *(const float4*)(qrow + 16*ks + 8*h);
            float4 b = *(const float4*)(qrow + 16*ks + 8*h + 4);
            a.x*=sc; a.y*=sc; a.z*=sc; a.w*=sc;
            b.x*=sc; b.y*=sc; b.z*=sc; b.w*=sc;
            qf[ks] = pack8(a, b);
        }
    }

    f32x16 accO[2];
    #pragma unroll
    for (int dm = 0; dm < 2; ++dm)
        #pragma unroll
        for (int i = 0; i < 16; ++i) accO[dm][i] = 0.f;
    float m_run = -1e30f, l_run = 0.f;

    // ---- staging mapping: thread -> (kv row, 16-float d-group) ----
    const int srow = tid >> 2;
    const int scg  = tid & 3;
    const float* kg0 = Kg + hbase + (size_t)srow * DHEAD + scg * 16;
    const float* vg0 = Vg + hbase + (size_t)srow * DHEAD + scg * 16;
    const int kwo0 = srow*64 + (((2*scg)   ^ (srow & 7)) << 3);
    const int kwo1 = srow*64 + (((2*scg+1) ^ (srow & 7)) << 3);
    const int kv4  = srow >> 2;
    const int psub = 16*(kv4>>2) + 8*(kv4&1) + 4*(scg>>1) + 2*((kv4>>1)&1) + (scg&1);
    const int vwo0 = psub*64 + (srow & 3)*16;

    const int ksw = (lq & 7) << 3;
    const u32 vbase0 = (u32)(size_t)(&vlds[0][0]) + (u32)lane * 8u;

    // prologue: load tile 0, stage into buf0; load tile 1 into regs
    float4 kr0,kr1,kr2,kr3, vr0,vr1,vr2,vr3;
    #define LOADKV(T) {                                                       \
        const float* kp = kg0 + (size_t)(T) * TILE_H;                          \
        const float* vp = vg0 + (size_t)(T) * TILE_H;                          \
        kr0 = *(const float4*)(kp+0); kr1 = *(const float4*)(kp+4);            \
        kr2 = *(const float4*)(kp+8); kr3 = *(const float4*)(kp+12);           \
        vr0 = *(const float4*)(vp+0); vr1 = *(const float4*)(vp+4);            \
        vr2 = *(const float4*)(vp+8); vr3 = *(const float4*)(vp+12); }
    #define STAGE(B) {                                                        \
        *(half8*)&klds[B][kwo0]   = pack8(kr0, kr1);                           \
        *(half8*)&klds[B][kwo1]   = pack8(kr2, kr3);                           \
        *(half8*)&vlds[B][vwo0]   = pack8(vr0, vr1);                           \
        *(half8*)&vlds[B][vwo0+8] = pack8(vr2, vr3); }

    LOADKV(0); STAGE(0);
    LOADKV(1);

    #pragma unroll 1
    for (int t = 0; t < NT; ++t) {
        const int cur = t & 1;
        __syncthreads();   // tile t staged; prior readers of buf[cur^1] done
        if (t + 1 < NT) STAGE(cur ^ 1);       // stage t+1 (regs from last iter)
        if (t + 2 < NT) LOADKV(t + 2);        // issue loads for t+2 (in flight 1 tile)

        // ---- S^T = K · Q^T : 2 kv m-tiles x 4 k-steps ----
        f32x16 sacc[2];
        __builtin_amdgcn_s_setprio(1);
        #pragma unroll
        for (int n = 0; n < 2; ++n) {
            #pragma unroll
            for (int i = 0; i < 16; ++i) sacc[n][i] = 0.f;
            #pragma unroll
            for (int ks = 0; ks < 4; ++ks) {
                half8 kf = *(const half8*)&klds[cur][(32*n + lq)*64 + ((16*ks + 8*h) ^ ksw)];
                sacc[n] = __builtin_amdgcn_mfma_f32_32x32x16_f16(kf, qf[ks], sacc[n], 0, 0, 0);
            }
        }
        __builtin_amdgcn_s_setprio(0);

        // ---- online softmax (exp2 domain, defer-max): q=lq lane-local ----
        float t16[16], t8[8], t4[4], t2[2];
        #pragma unroll
        for (int i = 0; i < 16; ++i) t16[i] = fmaxf(sacc[0][i], sacc[1][i]);
        #pragma unroll
        for (int i = 0; i < 8; ++i) t8[i] = fmaxf(t16[i], t16[i+8]);
        #pragma unroll
        for (int i = 0; i < 4; ++i) t4[i] = fmaxf(t8[i], t8[i+4]);
        t2[0] = fmaxf(t4[0], t4[2]); t2[1] = fmaxf(t4[1], t4[3]);
        float mx = fmaxf(t2[0], t2[1]);
        mx = fmaxf(mx, __shfl_xor(mx, 32, 64));

        const unsigned long long grow = __ballot(mx - m_run > 8.0f);
        if (grow != 0ull) {   // some row's max grew: rescale
            const float mnew = fmaxf(m_run, mx);
            const float alpha = fexp2(m_run - mnew);
            m_run = mnew;
            #pragma unroll
            for (int dm = 0; dm < 2; ++dm)
                #pragma unroll
                for (int i = 0; i < 16; ++i) accO[dm][i] *= alpha;
            l_run *= alpha;
        }
        #pragma unroll
        for (int n = 0; n < 2; ++n)
            #pragma unroll
            for (int i = 0; i < 16; ++i) sacc[n][i] = fexp2(sacc[n][i] - m_run);
        {
            float a16[16], a8[8], a4[4];
            #pragma unroll
            for (int i = 0; i < 16; ++i) a16[i] = sacc[0][i] + sacc[1][i];
            #pragma unroll
            for (int i = 0; i < 8; ++i) a8[i] = a16[i] + a16[i+8];
            #pragma unroll
            for (int i = 0; i < 4; ++i) a4[i] = a8[i] + a8[i+4];
            l_run += (a4[0] + a4[1]) + (a4[2] + a4[3]);
        }

        // pack P to f16 word pairs: c[n][b][rp] = regs (4b+2rp, 4b+2rp+1)
        u32 c[2][4][2];
        #pragma unroll
        for (int n = 0; n < 2; ++n)
            #pragma unroll
            for (int b = 0; b < 4; ++b)
                #pragma unroll
                for (int rp = 0; rp < 2; ++rp)
                    c[n][b][rp] = cvt2(sacc[n][4*b+2*rp], sacc[n][4*b+2*rp+1]);

        // ---- P^T B-fragments via lane<->lane+32 exchange (no LDS) ----
        half8 pb[4];
        #pragma unroll
        for (int ks2 = 0; ks2 < 4; ++ks2) {
            const int n = ks2 >> 1, k1 = ks2 & 1;
            union { u32 w[4]; half8 h; } pu;
            #pragma unroll
            for (int rp = 0; rp < 2; ++rp) {
                const u32 lo = c[n][2*k1][rp], hi = c[n][2*k1+1][rp];
                const u32 keep = h ? hi : lo;
                const u32 send = h ? lo : hi;
                const u32 other = (u32)__shfl_xor((int)send, 32, 64);
                pu.w[rp]   = h ? other : keep;   // slots for k-half 0
                pu.w[2+rp] = h ? keep  : other;  // slots for k-half 1
            }
            pb[ks2] = pu.h;
        }

        // ---- O^T += V^T · P^T : V via hardware transpose reads ----
        const u32 vb = vbase0 + (u32)(cur * (TILE_H * 2));   // byte offset of buffer
        half4v t000,t001,t010,t011,t100,t101,t110,t111,
               t200,t201,t210,t211,t300,t301,t310,t311;
        #define TRR(dst, IMM) \
            asm volatile("ds_read_b64_tr_b16 %0, %1 offset:" #IMM : "=v"(dst) : "v"(vb) : "memory")
        TRR(t000,    0); TRR(t001, 1024); TRR(t010,  512); TRR(t011, 1536);
        TRR(t100, 2048); TRR(t101, 3072); TRR(t110, 2560); TRR(t111, 3584);
        TRR(t200, 4096); TRR(t201, 5120); TRR(t210, 4608); TRR(t211, 5632);
        TRR(t300, 6144); TRR(t301, 7168); TRR(t310, 6656); TRR(t311, 7680);
        #undef TRR
        asm volatile("s_waitcnt lgkmcnt(0)" ::: "memory");
        __builtin_amdgcn_sched_barrier(0);

        __builtin_amdgcn_s_setprio(1);
        #define PVM(ks, dm, ta, tb) { half8 vv;                                   \
            vv[0]=ta[0]; vv[1]=ta[1]; vv[2]=ta[2]; vv[3]=ta[3];                    \
            vv[4]=tb[0]; vv[5]=tb[1]; vv[6]=tb[2]; vv[7]=tb[3];                    \
            accO[dm] = __builtin_amdgcn_mfma_f32_32x32x16_f16(vv, pb[ks], accO[dm], 0, 0, 0); }
        PVM(0,0,t000,t001) PVM(0,1,t010,t011)
        PVM(1,0,t100,t101) PVM(1,1,t110,t111)
        PVM(2,0,t200,t201) PVM(2,1,t210,t211)
        PVM(3,0,t300,t301) PVM(3,1,t310,t311)
        #undef PVM
        __builtin_amdgcn_s_setprio(0);
    }
    #undef LOADKV
    #undef STAGE

    // ---- epilogue ----
    const float ltot = l_run + __shfl_xor(l_run, 32, 64);
    const float inv = 1.0f / ltot;
    float* orow = Og + hbase + (size_t)(q0 + lq) * DHEAD;
    #pragma unroll
    for (int dm = 0; dm < 2; ++dm)
        #pragma unroll
        for (int b = 0; b < 4; ++b) {
            float4 o;
            o.x = accO[dm][4*b+0] * inv;
            o.y = accO[dm][4*b+1] * inv;
            o.z = accO[dm][4*b+2] * inv;
            o.w = accO[dm][4*b+3] * inv;
            *(float4*)(orow + 32*dm + 8*b + 4*h) = o;
        }
}

extern "C" void kernel_launch(void* const* d_in, const int* in_sizes, int n_in,
                              void* d_out, int out_size, void* d_ws, size_t ws_size,
                              hipStream_t stream) {
    const float* Q = (const float*)d_in[0];
    const float* K = (const float*)d_in[1];
    const float* V = (const float*)d_in[2];
    float* O = (float*)d_out;
    dim3 grid(32 * (SEQ / QBLK));   // 32 heads * 16 q-blocks = 512
    fattn_fwd<<<grid, 256, 0, stream>>>(Q, K, V, O);
}